// Round 1
// baseline (401.239 us; speedup 1.0000x reference)
//
#include <hip/hip_runtime.h>

#define N_BATCH 8192
#define S 14
#define N_CELLS (N_BATCH * S * S)

__global__ __launch_bounds__(256) void yolo_loss_kernel(
    const float* __restrict__ pred, const float* __restrict__ targ,
    float* __restrict__ out)
{
    const int cell = blockIdx.x * blockDim.x + threadIdx.x;
    float total = 0.0f;

    if (cell < N_CELLS) {
        float p[30], t[30];
        // 120 B per cell -> always 8 B aligned; use float2 loads.
        const float2* pp = reinterpret_cast<const float2*>(pred + (size_t)cell * 30);
        const float2* tp = reinterpret_cast<const float2*>(targ + (size_t)cell * 30);
#pragma unroll
        for (int i = 0; i < 15; ++i) {
            float2 v = pp[i]; p[2 * i] = v.x; p[2 * i + 1] = v.y;
            float2 w = tp[i]; t[2 * i] = w.x; t[2 * i + 1] = w.y;
        }

        const float INV14 = 1.0f / 14.0f;
        const float objf = (t[4] > 0.0f) ? 1.0f : 0.0f;
        const float noof = 1.0f - objf;

        // no-object confidence loss (conf slots 4 and 9)
        const float d4 = p[4] - t[4];
        const float d9 = p[9] - t[9];
        const float nooobj = noof * (d4 * d4 + d9 * d9);

        // target box 0 -> xyxy
        const float tx = t[0] * INV14, ty = t[1] * INV14;
        const float tw = t[2], th = t[3];
        const float tx1 = tx - 0.5f * tw, ty1 = ty - 0.5f * th;
        const float tx2 = tx + 0.5f * tw, ty2 = ty + 0.5f * th;
        const float area_t = (tx2 - tx1) * (ty2 - ty1);

        float iou[2];
#pragma unroll
        for (int b = 0; b < 2; ++b) {
            const float* pb = p + 5 * b;
            const float px = pb[0] * INV14, py = pb[1] * INV14;
            const float pw = pb[2], ph = pb[3];
            const float px1 = px - 0.5f * pw, py1 = py - 0.5f * ph;
            const float px2 = px + 0.5f * pw, py2 = py + 0.5f * ph;
            const float ltx = fmaxf(px1, tx1), lty = fmaxf(py1, ty1);
            const float rbx = fminf(px2, tx2), rby = fminf(py2, ty2);
            const float wx = fmaxf(rbx - ltx, 0.0f);
            const float wy = fmaxf(rby - lty, 0.0f);
            const float inter = wx * wy;
            const float area_p = (px2 - px1) * (py2 - py1);
            iou[b] = inter / (area_p + area_t - inter);
        }

        // argmax over 2 boxes; ties -> index 0 (jnp.argmax first-max)
        const int r = (iou[1] > iou[0]) ? 1 : 0;
        const float max_iou = fmaxf(iou[0], iou[1]);

        const float pc = p[5 * r + 4];
        const float contain = objf * (pc - max_iou) * (pc - max_iou);
        const float pnc = p[5 * (1 - r) + 4];
        const float not_contain = objf * pnc * pnc;

        // localization loss: responsible box vs per-box target slice tb[..., r, :]
        const float dx = p[5 * r + 0] - t[5 * r + 0];
        const float dy = p[5 * r + 1] - t[5 * r + 1];
        const float dw = sqrtf(p[5 * r + 2]) - sqrtf(t[5 * r + 2]);
        const float dh = sqrtf(p[5 * r + 3]) - sqrtf(t[5 * r + 3]);
        const float loc = objf * (dx * dx + dy * dy + dw * dw + dh * dh);

        float cls = 0.0f;
#pragma unroll
        for (int k = 10; k < 30; ++k) {
            const float d = p[k] - t[k];
            cls += d * d;
        }
        cls *= objf;

        total = (5.0f * loc + 2.0f * contain + 0.5f * nooobj + cls + not_contain)
              * (1.0f / (float)N_BATCH);
    }

    // 64-lane wave reduction
#pragma unroll
    for (int off = 32; off > 0; off >>= 1)
        total += __shfl_down(total, off, 64);

    __shared__ float sdata[4];  // 256 threads / 64 = 4 waves
    const int lane = threadIdx.x & 63;
    const int wave = threadIdx.x >> 6;
    if (lane == 0) sdata[wave] = total;
    __syncthreads();
    if (threadIdx.x == 0) {
        const float s = sdata[0] + sdata[1] + sdata[2] + sdata[3];
        atomicAdd(out, s);
    }
}

extern "C" void kernel_launch(void* const* d_in, const int* in_sizes, int n_in,
                              void* d_out, int out_size, void* d_ws, size_t ws_size,
                              hipStream_t stream) {
    const float* pred = (const float*)d_in[0];
    const float* targ = (const float*)d_in[1];
    float* out = (float*)d_out;

    hipMemsetAsync(out, 0, sizeof(float), stream);

    const int threads = 256;
    const int blocks = (N_CELLS + threads - 1) / threads;
    yolo_loss_kernel<<<blocks, threads, 0, stream>>>(pred, targ, out);
}

// Round 2
// 385.677 us; speedup vs baseline: 1.0403x; 1.0403x over previous
//
#include <hip/hip_runtime.h>

#define N_BATCH 8192
#define S 14
#define N_CELLS (N_BATCH * S * S)

#define TILE 256                      // cells per block
#define FPC 30                        // floats per cell
#define TILE_FLOATS (TILE * FPC)      // 7680 floats = 30720 B per tensor
#define TILE_F4 (TILE_FLOATS / 4)     // 1920 float4 per tensor

__global__ __launch_bounds__(256) void yolo_loss_kernel(
    const float* __restrict__ pred, const float* __restrict__ targ,
    float* __restrict__ out)
{
    __shared__ float sp[TILE_FLOATS];   // 30 KB
    __shared__ float st[TILE_FLOATS];   // 30 KB

    const int tid = threadIdx.x;
    const size_t tile_base = (size_t)blockIdx.x * TILE_FLOATS;  // 30720 B/block -> 16B aligned

    // ---- stage: fully coalesced float4 global loads -> LDS (b128 writes) ----
    const float4* gp = reinterpret_cast<const float4*>(pred + tile_base);
    const float4* gt = reinterpret_cast<const float4*>(targ + tile_base);
    float4* lp = reinterpret_cast<float4*>(sp);
    float4* lt = reinterpret_cast<float4*>(st);
#pragma unroll
    for (int i = 0; i < 8; ++i) {
        const int idx = tid + i * 256;
        if (idx < TILE_F4) {            // iters 0..6 full, iter 7 half-active
            lp[idx] = gp[idx];
            lt[idx] = gt[idx];
        }
    }
    __syncthreads();

    // ---- compute: one cell per thread, data from LDS ----
    const float* p = sp + tid * FPC;
    const float* t = st + tid * FPC;

    const float INV14 = 1.0f / 14.0f;
    const float objf = (t[4] > 0.0f) ? 1.0f : 0.0f;
    const float noof = 1.0f - objf;

    // no-object confidence loss (conf slots 4 and 9)
    const float d4 = p[4] - t[4];
    const float d9 = p[9] - t[9];
    const float nooobj = noof * (d4 * d4 + d9 * d9);

    // target box 0 -> xyxy
    const float tx = t[0] * INV14, ty = t[1] * INV14;
    const float tw = t[2], th = t[3];
    const float tx1 = tx - 0.5f * tw, ty1 = ty - 0.5f * th;
    const float tx2 = tx + 0.5f * tw, ty2 = ty + 0.5f * th;
    const float area_t = (tx2 - tx1) * (ty2 - ty1);

    float iou[2];
#pragma unroll
    for (int b = 0; b < 2; ++b) {
        const float px = p[5 * b + 0] * INV14, py = p[5 * b + 1] * INV14;
        const float pw = p[5 * b + 2], ph = p[5 * b + 3];
        const float px1 = px - 0.5f * pw, py1 = py - 0.5f * ph;
        const float px2 = px + 0.5f * pw, py2 = py + 0.5f * ph;
        const float ltx = fmaxf(px1, tx1), lty = fmaxf(py1, ty1);
        const float rbx = fminf(px2, tx2), rby = fminf(py2, ty2);
        const float wx = fmaxf(rbx - ltx, 0.0f);
        const float wy = fmaxf(rby - lty, 0.0f);
        const float inter = wx * wy;
        const float area_p = (px2 - px1) * (py2 - py1);
        iou[b] = inter / (area_p + area_t - inter);
    }

    // argmax over 2 boxes; ties -> index 0 (jnp.argmax first-max)
    const int r = (iou[1] > iou[0]) ? 1 : 0;
    const float max_iou = fmaxf(iou[0], iou[1]);

    const float pc = p[5 * r + 4];
    const float contain = objf * (pc - max_iou) * (pc - max_iou);
    const float pnc = p[5 * (1 - r) + 4];
    const float not_contain = objf * pnc * pnc;

    // localization loss: responsible box vs per-box target slice tb[..., r, :]
    const float dx = p[5 * r + 0] - t[5 * r + 0];
    const float dy = p[5 * r + 1] - t[5 * r + 1];
    const float dw = sqrtf(p[5 * r + 2]) - sqrtf(t[5 * r + 2]);
    const float dh = sqrtf(p[5 * r + 3]) - sqrtf(t[5 * r + 3]);
    const float loc = objf * (dx * dx + dy * dy + dw * dw + dh * dh);

    float cls = 0.0f;
#pragma unroll
    for (int k = 10; k < 30; ++k) {
        const float d = p[k] - t[k];
        cls += d * d;
    }
    cls *= objf;

    float total = (5.0f * loc + 2.0f * contain + 0.5f * nooobj + cls + not_contain)
                * (1.0f / (float)N_BATCH);

    // ---- 64-lane wave reduction -> per-block atomic ----
#pragma unroll
    for (int off = 32; off > 0; off >>= 1)
        total += __shfl_down(total, off, 64);

    __shared__ float sdata[4];  // 256 threads / 64 = 4 waves
    const int lane = tid & 63;
    const int wave = tid >> 6;
    if (lane == 0) sdata[wave] = total;
    __syncthreads();
    if (tid == 0) {
        const float s = sdata[0] + sdata[1] + sdata[2] + sdata[3];
        atomicAdd(out, s);
    }
}

extern "C" void kernel_launch(void* const* d_in, const int* in_sizes, int n_in,
                              void* d_out, int out_size, void* d_ws, size_t ws_size,
                              hipStream_t stream) {
    const float* pred = (const float*)d_in[0];
    const float* targ = (const float*)d_in[1];
    float* out = (float*)d_out;

    hipMemsetAsync(out, 0, sizeof(float), stream);

    const int blocks = N_CELLS / TILE;  // 1605632 / 256 = 6272 exactly
    yolo_loss_kernel<<<blocks, TILE, 0, stream>>>(pred, targ, out);
}